// Round 1
// baseline (15.734 us; speedup 1.0000x reference)
//
#include <hip/hip_runtime.h>

// HungarianMatcher cost matrix: out[b,q,t] = 1*cost_class + 5*cost_l1 + 2*(-giou)
// vs batch-0 targets only (reference slices [:, :, :T] of the bs*T axis).
// bs=64, Q=300, C=13, T=32. One thread per (b,q); 32 outputs per thread.

constexpr int QN = 300;
constexpr int NC = 13;
constexpr int T  = 32;
constexpr float W_CLASS = 1.0f;
constexpr float W_BBOX  = 5.0f;
constexpr float W_GIOU  = 2.0f;

constexpr int BLK = 64;

__global__ __launch_bounds__(BLK) void matcher_kernel(
    const float* __restrict__ pred_logits,   // [64,300,13]
    const float* __restrict__ pred_boxes,    // [64,300,4] cxcywh
    const float* __restrict__ tgt_boxes,     // [64,32,4] cxcywh (only batch 0 used)
    const int*   __restrict__ tgt_ids,       // [64,32]    (only batch 0 used)
    float* __restrict__ out)                 // [64,300,32]
{
    // per-block target tables (batch 0 only)
    __shared__ float t_cx[T], t_cy[T], t_w[T], t_h[T];
    __shared__ float t_x0[T], t_y0[T], t_x1[T], t_y1[T], t_area[T];
    __shared__ int   t_id[T];
    // per-thread softmax probs; stride 13 is coprime with 32 banks -> conflict-free
    __shared__ float probs[BLK][NC];

    const int tid = threadIdx.x;
    if (tid < T) {
        float4 tb = *(const float4*)(tgt_boxes + tid * 4);   // 16B-aligned
        float cx = tb.x, cy = tb.y, w = tb.z, h = tb.w;
        float x0 = cx - 0.5f * w, y0 = cy - 0.5f * h;
        float x1 = cx + 0.5f * w, y1 = cy + 0.5f * h;
        t_cx[tid] = cx; t_cy[tid] = cy; t_w[tid] = w; t_h[tid] = h;
        t_x0[tid] = x0; t_y0[tid] = y0; t_x1[tid] = x1; t_y1[tid] = y1;
        t_area[tid] = (x1 - x0) * (y1 - y0);
        t_id[tid] = tgt_ids[tid];
    }

    const int g = blockIdx.x * BLK + tid;     // query index in [0, 19200)

    // ---- softmax over 13 logits ----
    const float* lg = pred_logits + (size_t)g * NC;
    float l[NC];
    #pragma unroll
    for (int c = 0; c < NC; ++c) l[c] = lg[c];
    float m = l[0];
    #pragma unroll
    for (int c = 1; c < NC; ++c) m = fmaxf(m, l[c]);
    float s = 0.0f;
    #pragma unroll
    for (int c = 0; c < NC; ++c) { l[c] = __expf(l[c] - m); s += l[c]; }
    float inv = 1.0f / s;
    #pragma unroll
    for (int c = 0; c < NC; ++c) probs[tid][c] = l[c] * inv;

    // ---- pred box ----
    float4 pb = *(const float4*)(pred_boxes + (size_t)g * 4);  // cx,cy,w,h
    float px0 = pb.x - 0.5f * pb.z, py0 = pb.y - 0.5f * pb.w;
    float px1 = pb.x + 0.5f * pb.z, py1 = pb.y + 0.5f * pb.w;
    float parea = (px1 - px0) * (py1 - py0);

    __syncthreads();

    float res[T];
    #pragma unroll
    for (int t = 0; t < T; ++t) {
        // classification: -P[id]  (runtime LDS index, stride-13 row)
        float cls = -probs[tid][t_id[t]];
        // L1 on raw cxcywh
        float cb = fabsf(pb.x - t_cx[t]) + fabsf(pb.y - t_cy[t])
                 + fabsf(pb.z - t_w[t])  + fabsf(pb.w - t_h[t]);
        // GIoU on xyxy
        float ltx = fmaxf(px0, t_x0[t]), lty = fmaxf(py0, t_y0[t]);
        float rbx = fminf(px1, t_x1[t]), rby = fminf(py1, t_y1[t]);
        float iw = fmaxf(rbx - ltx, 0.0f), ih = fmaxf(rby - lty, 0.0f);
        float inter = iw * ih;
        float uni = parea + t_area[t] - inter;
        float iou = inter / uni;
        float ex0 = fminf(px0, t_x0[t]), ey0 = fminf(py0, t_y0[t]);
        float ex1 = fmaxf(px1, t_x1[t]), ey1 = fmaxf(py1, t_y1[t]);
        float ew = fmaxf(ex1 - ex0, 0.0f), eh = fmaxf(ey1 - ey0, 0.0f);
        float earea = ew * eh;
        float giou = iou - (earea - uni) / earea;
        res[t] = W_CLASS * cls + W_BBOX * cb - W_GIOU * giou;
    }

    // ---- store 32 contiguous f32 as 8x float4 ----
    float* o = out + (size_t)g * T;
    #pragma unroll
    for (int t4 = 0; t4 < T / 4; ++t4) {
        float4 v;
        v.x = res[t4 * 4 + 0];
        v.y = res[t4 * 4 + 1];
        v.z = res[t4 * 4 + 2];
        v.w = res[t4 * 4 + 3];
        *(float4*)(o + t4 * 4) = v;
    }
}

extern "C" void kernel_launch(void* const* d_in, const int* in_sizes, int n_in,
                              void* d_out, int out_size, void* d_ws, size_t ws_size,
                              hipStream_t stream) {
    const float* pred_logits = (const float*)d_in[0];
    const float* pred_boxes  = (const float*)d_in[1];
    const float* tgt_boxes   = (const float*)d_in[2];
    const int*   tgt_ids     = (const int*)d_in[3];
    float* out = (float*)d_out;

    const int total = 64 * QN;            // 19200 queries
    const int grid = total / BLK;         // 300 blocks
    matcher_kernel<<<grid, BLK, 0, stream>>>(pred_logits, pred_boxes,
                                             tgt_boxes, tgt_ids, out);
}

// Round 2
// 9.910 us; speedup vs baseline: 1.5877x; 1.5877x over previous
//
#include <hip/hip_runtime.h>

// HungarianMatcher cost matrix: out[b,q,t] = cls + 5*L1 - 2*giou
// vs batch-0 targets only (reference slices [:, :, :T] of the bs*T axis).
// bs=64, Q=300, C=13, T=32.
// Round 2: 8 threads per query (4 targets each), no LDS, no barriers ->
// 2400 waves (~9.4/CU) for latency hiding instead of 300.

constexpr int QN = 300;
constexpr int NC = 13;
constexpr int T  = 32;
constexpr float W_BBOX = 5.0f;
constexpr float W_GIOU = 2.0f;

constexpr int BLK = 256;
constexpr int TPQ = 8;        // threads per query
constexpr int TGT = T / TPQ;  // 4 targets per thread

__global__ __launch_bounds__(BLK) void matcher_kernel(
    const float* __restrict__ pred_logits,   // [64,300,13]
    const float* __restrict__ pred_boxes,    // [64,300,4] cxcywh
    const float* __restrict__ tgt_boxes,     // [64,32,4] cxcywh (batch 0 only)
    const int*   __restrict__ tgt_ids,       // [64,32]    (batch 0 only)
    float* __restrict__ out)                 // [64,300,32]
{
    const int gtid = blockIdx.x * BLK + threadIdx.x;
    const int q   = gtid >> 3;        // query index in [0, 19200)
    const int sub = gtid & 7;         // which 4-target slice

    // ---- softmax over 13 logits (redundant x8 per query; L1-cached) ----
    const float* lg = pred_logits + (size_t)q * NC;
    float l[NC];
    #pragma unroll
    for (int c = 0; c < NC; ++c) l[c] = lg[c];
    float m = l[0];
    #pragma unroll
    for (int c = 1; c < NC; ++c) m = fmaxf(m, l[c]);
    float s = 0.0f;
    #pragma unroll
    for (int c = 0; c < NC; ++c) { l[c] = __expf(l[c] - m); s += l[c]; }
    float inv = 1.0f / s;
    #pragma unroll
    for (int c = 0; c < NC; ++c) l[c] *= inv;   // l[] now holds probs

    // ---- pred box ----
    float4 pb = *(const float4*)(pred_boxes + (size_t)q * 4);  // cx,cy,w,h
    float px0 = pb.x - 0.5f * pb.z, py0 = pb.y - 0.5f * pb.w;
    float px1 = pb.x + 0.5f * pb.z, py1 = pb.y + 0.5f * pb.w;
    float parea = (px1 - px0) * (py1 - py0);

    const int t0 = sub * TGT;
    float res[TGT];
    #pragma unroll
    for (int k = 0; k < TGT; ++k) {
        const int t = t0 + k;
        float4 tb = *(const float4*)(tgt_boxes + t * 4);   // L1-resident, 512B total
        int id = tgt_ids[t];

        // classification: -P[id] via unrolled register select (no scratch, no LDS)
        float p = l[0];
        #pragma unroll
        for (int c = 1; c < NC; ++c) p = (id == c) ? l[c] : p;

        // L1 on raw cxcywh
        float cb = fabsf(pb.x - tb.x) + fabsf(pb.y - tb.y)
                 + fabsf(pb.z - tb.z) + fabsf(pb.w - tb.w);

        // GIoU on xyxy
        float tx0 = tb.x - 0.5f * tb.z, ty0 = tb.y - 0.5f * tb.w;
        float tx1 = tb.x + 0.5f * tb.z, ty1 = tb.y + 0.5f * tb.w;
        float tarea = (tx1 - tx0) * (ty1 - ty0);

        float ltx = fmaxf(px0, tx0), lty = fmaxf(py0, ty0);
        float rbx = fminf(px1, tx1), rby = fminf(py1, ty1);
        float iw = fmaxf(rbx - ltx, 0.0f), ih = fmaxf(rby - lty, 0.0f);
        float inter = iw * ih;
        float uni = parea + tarea - inter;
        float iou = inter / uni;
        float ex0 = fminf(px0, tx0), ey0 = fminf(py0, ty0);
        float ex1 = fmaxf(px1, tx1), ey1 = fmaxf(py1, ty1);
        float earea = (ex1 - ex0) * (ey1 - ey0);   // >=0 by construction
        float giou = iou - (earea - uni) / earea;

        res[k] = -p + W_BBOX * cb - W_GIOU * giou;
    }

    // ---- store 4 contiguous f32 as one float4 (subs tile the 128B row) ----
    float* o = out + (size_t)q * T + t0;
    float4 v; v.x = res[0]; v.y = res[1]; v.z = res[2]; v.w = res[3];
    *(float4*)o = v;
}

extern "C" void kernel_launch(void* const* d_in, const int* in_sizes, int n_in,
                              void* d_out, int out_size, void* d_ws, size_t ws_size,
                              hipStream_t stream) {
    const float* pred_logits = (const float*)d_in[0];
    const float* pred_boxes  = (const float*)d_in[1];
    const float* tgt_boxes   = (const float*)d_in[2];
    const int*   tgt_ids     = (const int*)d_in[3];
    float* out = (float*)d_out;

    const int total = 64 * QN * TPQ;      // 153600 threads
    const int grid = total / BLK;         // 600 blocks
    matcher_kernel<<<grid, BLK, 0, stream>>>(pred_logits, pred_boxes,
                                             tgt_boxes, tgt_ids, out);
}

// Round 3
// 9.824 us; speedup vs baseline: 1.6017x; 1.0088x over previous
//
#include <hip/hip_runtime.h>

// HungarianMatcher cost matrix: out[b,q,t] = -P[id_t] + 5*L1 - 2*giou
// vs batch-0 targets only (reference slices [:, :, :T] of the bs*T axis).
// bs=64, Q=300, C=13, T=32.
// Round 3: 16 lanes per query. Cooperative softmax via __shfl_xor(width=16):
// each lane loads ONE logit, butterfly max+sum, prob gather = one __shfl.
// Each lane then computes 2 targets and stores a float2.
// 4800 waves (~18.7/CU), ~90 VALU ops/thread, 1 logit load/thread.

constexpr int QN = 300;
constexpr int NC = 13;
constexpr int T  = 32;
constexpr float W_BBOX = 5.0f;
constexpr float W_GIOU = 2.0f;

constexpr int BLK = 256;
constexpr int LPQ = 16;                   // lanes per query
constexpr int QPB = BLK / LPQ;            // 16 queries per block

__device__ __forceinline__ float cost_one(
    float4 pb, float px0, float py0, float px1, float py1, float parea,
    float4 tb, float p)
{
    // L1 on raw cxcywh
    float cb = fabsf(pb.x - tb.x) + fabsf(pb.y - tb.y)
             + fabsf(pb.z - tb.z) + fabsf(pb.w - tb.w);
    // GIoU on xyxy
    float tx0 = tb.x - 0.5f * tb.z, ty0 = tb.y - 0.5f * tb.w;
    float tx1 = tb.x + 0.5f * tb.z, ty1 = tb.y + 0.5f * tb.w;
    float tarea = (tx1 - tx0) * (ty1 - ty0);
    float ltx = fmaxf(px0, tx0), lty = fmaxf(py0, ty0);
    float rbx = fminf(px1, tx1), rby = fminf(py1, ty1);
    float iw = fmaxf(rbx - ltx, 0.0f), ih = fmaxf(rby - lty, 0.0f);
    float inter = iw * ih;
    float uni = parea + tarea - inter;
    float iou = inter / uni;
    float ex0 = fminf(px0, tx0), ey0 = fminf(py0, ty0);
    float ex1 = fmaxf(px1, tx1), ey1 = fmaxf(py1, ty1);
    float earea = (ex1 - ex0) * (ey1 - ey0);   // >= 0 by construction
    float giou = iou - (earea - uni) / earea;
    return -p + W_BBOX * cb - W_GIOU * giou;
}

__global__ __launch_bounds__(BLK) void matcher_kernel(
    const float* __restrict__ pred_logits,   // [64,300,13]
    const float* __restrict__ pred_boxes,    // [64,300,4] cxcywh
    const float* __restrict__ tgt_boxes,     // [64,32,4] cxcywh (batch 0 only)
    const int*   __restrict__ tgt_ids,       // [64,32]    (batch 0 only)
    float* __restrict__ out)                 // [64,300,32]
{
    const int tid = threadIdx.x;
    const int j = tid & (LPQ - 1);                     // lane-in-group 0..15
    const int q = blockIdx.x * QPB + (tid >> 4);       // query 0..19199

    // ---- cooperative softmax: lane j owns logit j (j<13) ----
    float lv = (j < NC) ? pred_logits[(size_t)q * NC + j] : -1e30f;
    float m = lv;
    #pragma unroll
    for (int mask = 8; mask >= 1; mask >>= 1)
        m = fmaxf(m, __shfl_xor(m, mask, LPQ));
    float e = (j < NC) ? __expf(lv - m) : 0.0f;
    float s = e;
    #pragma unroll
    for (int mask = 8; mask >= 1; mask >>= 1)
        s += __shfl_xor(s, mask, LPQ);
    float prob = e / s;                                // lane j holds P[j]

    // ---- pred box (same addr across group -> cache broadcast) ----
    float4 pb = *(const float4*)(pred_boxes + (size_t)q * 4);
    float px0 = pb.x - 0.5f * pb.z, py0 = pb.y - 0.5f * pb.w;
    float px1 = pb.x + 0.5f * pb.z, py1 = pb.y + 0.5f * pb.w;
    float parea = (px1 - px0) * (py1 - py0);

    // ---- lane j handles targets 2j, 2j+1 ----
    int2 ids = *(const int2*)(tgt_ids + 2 * j);        // 8B aligned
    float4 tb0 = *(const float4*)(tgt_boxes + (size_t)(2 * j) * 4);
    float4 tb1 = *(const float4*)(tgt_boxes + (size_t)(2 * j + 1) * 4);
    float p0 = __shfl(prob, ids.x, LPQ);               // P[id] gather
    float p1 = __shfl(prob, ids.y, LPQ);

    float c0 = cost_one(pb, px0, py0, px1, py1, parea, tb0, p0);
    float c1 = cost_one(pb, px0, py0, px1, py1, parea, tb1, p1);

    float2 v; v.x = c0; v.y = c1;
    *(float2*)(out + (size_t)q * T + 2 * j) = v;       // 8B aligned
}

extern "C" void kernel_launch(void* const* d_in, const int* in_sizes, int n_in,
                              void* d_out, int out_size, void* d_ws, size_t ws_size,
                              hipStream_t stream) {
    const float* pred_logits = (const float*)d_in[0];
    const float* pred_boxes  = (const float*)d_in[1];
    const float* tgt_boxes   = (const float*)d_in[2];
    const int*   tgt_ids     = (const int*)d_in[3];
    float* out = (float*)d_out;

    const int total_q = 64 * QN;              // 19200 queries
    const int grid = total_q / QPB;           // 1200 blocks of 256
    matcher_kernel<<<grid, BLK, 0, stream>>>(pred_logits, pred_boxes,
                                             tgt_boxes, tgt_ids, out);
}